// Round 10
// baseline (516.690 us; speedup 1.0000x reference)
//
#include <hip/hip_runtime.h>
#include <hip/hip_bf16.h>

// VarianceAdaptor: 3x (conv1d->relu->LN->conv1d->relu->LN->linear) predictors,
// embedding adds between them, then length-regulate.
// Shapes fixed: B=32, S=512, D=F=512, K=3, T=4096, NB=256.
// Round 10: conv occupancy 2x -> 4 waves/SIMD: BM=32, BN=512, BK=32,
// grid=512 = 2 blocks/CU x 8 waves (16 waves/CU), LDS 72KB/block,
// __launch_bounds__(512,4) caps VGPR<=128. R5-proven 2-phase syncthreads
// staging (sibling block covers the drain). LN(+linear) epilogue fusion kept.

#define B_ 32
#define S_ 512
#define D_ 512
#define F_ 512
#define T_ 4096
#define SP_ 514           // padded rows per batch (row0 and row513 are zeros)
#define KK_ 1536          // 3*512 contraction length
#define NKT 48            // 1536/32 K-tiles

typedef __attribute__((ext_vector_type(8))) short bf16x8;
typedef __attribute__((ext_vector_type(4))) float f32x4;

__device__ __forceinline__ float bf2f(unsigned short u) {
  union { unsigned int i; float f; } c; c.i = (unsigned int)u << 16; return c.f;
}
__device__ __forceinline__ unsigned short f2bf(float f) {
  __hip_bfloat16 h = __float2bfloat16(f);
  return *(unsigned short*)&h;
}

// ------ fp32 [B][512][512] -> bf16 padded X0 rows 1..512; tail zeroes pads ---
__global__ __launch_bounds__(128) void topad_k(const float* __restrict__ in,
                                               __hip_bfloat16* __restrict__ X0,
                                               __hip_bfloat16* __restrict__ X,
                                               __hip_bfloat16* __restrict__ P) {
  if (blockIdx.x >= (unsigned)B_ * S_) {         // 64 pad blocks: zero pad rows
    const int idx = blockIdx.x - B_ * S_;
    const int b = idx >> 1;
    const int r = (idx & 1) ? (SP_ - 1) : 0;
    const size_t off = ((size_t)b * SP_ + r) * D_ + threadIdx.x * 4;
    const ushort4 z = make_ushort4(0, 0, 0, 0);
    *(ushort4*)((unsigned short*)X0 + off) = z;
    *(ushort4*)((unsigned short*)X + off) = z;
    *(ushort4*)((unsigned short*)P + off) = z;
    return;
  }
  const int row = blockIdx.x;          // b*512 + s
  const int b = row >> 9, s = row & 511;
  const float4 v = *(const float4*)(in + (size_t)row * D_ + threadIdx.x * 4);
  ushort4 u = make_ushort4(f2bf(v.x), f2bf(v.y), f2bf(v.z), f2bf(v.w));
  *(ushort4*)((unsigned short*)X0 + ((size_t)b * SP_ + s + 1) * D_ + threadIdx.x * 4) = u;
}

// ---------------- W [1536][512] fp32 -> WT [512][1536] bf16 (6 matrices) -----
__global__ __launch_bounds__(256) void wtrans_k(const float* __restrict__ W1,
                                                const float* __restrict__ W2,
                                                __hip_bfloat16* __restrict__ WT1,
                                                __hip_bfloat16* __restrict__ WT2) {
  __shared__ float tb[64][65];
  const int bid = blockIdx.x;          // w*192 + kt*8 + ft
  const int w = bid / 192;
  const int kt = (bid % 192) >> 3;     // 24 kk-tiles of 64
  const int ft = bid & 7;              // 8 f-tiles of 64
  const float* src = (w < 3) ? (W1 + (size_t)w * KK_ * F_)
                             : (W2 + (size_t)(w - 3) * KK_ * F_);
  __hip_bfloat16* dst = (w < 3) ? (WT1 + (size_t)w * KK_ * F_)
                                : (WT2 + (size_t)(w - 3) * KK_ * F_);
  const int ty = threadIdx.x >> 4, tx = threadIdx.x & 15;
  #pragma unroll
  for (int j = 0; j < 4; ++j) {
    const int r = ty + j * 16;         // kk within tile
    const float4 v = *(const float4*)(src + (size_t)(kt * 64 + r) * F_ + ft * 64 + tx * 4);
    tb[r][tx * 4 + 0] = v.x; tb[r][tx * 4 + 1] = v.y;
    tb[r][tx * 4 + 2] = v.z; tb[r][tx * 4 + 3] = v.w;
  }
  __syncthreads();
  #pragma unroll
  for (int j = 0; j < 4; ++j) {
    const int r = ty + j * 16;         // f within tile
    ushort4 u = make_ushort4(f2bf(tb[tx * 4 + 0][r]), f2bf(tb[tx * 4 + 1][r]),
                             f2bf(tb[tx * 4 + 2][r]), f2bf(tb[tx * 4 + 3][r]));
    *(ushort4*)((unsigned short*)dst + (size_t)(ft * 64 + r) * KK_ + kt * 64 + tx * 4) = u;
  }
}

// ----- conv + bias + relu + LayerNorm fused. MODE 0: -> bf16 padded Pout.
// ----- MODE 1: + linear head -> pred only.
// Y[b*512+st+i][f] = sum_kk Pin[b][st+i+(kk/512)][kk%512] * WT[f][kk]
template <int MODE>
__global__ __launch_bounds__(512, 4) void convfuse_k(
    const __hip_bfloat16* __restrict__ Pin,
    const __hip_bfloat16* __restrict__ WT,
    const float* __restrict__ bias,
    const float* __restrict__ g,
    const float* __restrict__ be,
    const float* __restrict__ wl,
    const float* __restrict__ bl,
    const unsigned char* __restrict__ mask,
    __hip_bfloat16* __restrict__ Pout,
    float* __restrict__ pred) {
  extern __shared__ char smem[];
  char* As = smem;                     // 2 x 4096  [32 rows][64 B]
  char* Bs = smem + 2 * 4096;          // 2 x 32768 [512 f][64 B]
  // T1: XCD swizzle (512 blocks, 8 XCDs -> 64 contiguous M-tiles per XCD).
  const int swz = (blockIdx.x & 7) * 64 + (blockIdx.x >> 3);
  const int b  = swz >> 4;             // 16 M-tiles per batch
  const int st = (swz & 15) * 32;
  const int t = threadIdx.x;
  const int lane = t & 63;
  const int wave = t >> 6;
  const int wn = wave * 64;            // wave's 64-col slice; all waves same rows

  f32x4 acc[2][4];
  #pragma unroll
  for (int m = 0; m < 2; ++m)
    #pragma unroll
    for (int n = 0; n < 4; ++n) acc[m][n] = (f32x4){0.f, 0.f, 0.f, 0.f};

  const __hip_bfloat16* Xb = Pin + (size_t)b * SP_ * D_;

  // Stage one K-tile (K=32). A: 128 chunks (threads 0-127, 1 ea); B: 2048
  // chunks (4/thread). T2: pre-swizzled global source ch^(row&3), lane-linear
  // LDS dest (global_load_lds contract). kk base for WT row = kt*32.
  auto stage = [&](int kt, int buf) {
    const int tap = kt >> 4, d0 = (kt & 15) * 32;
    char* Ad = As + buf * 4096;
    if (t < 128) {
      const int row = t >> 2, ch = t & 3;
      const __hip_bfloat16* ga =
          Xb + (size_t)(st + tap + row) * D_ + d0 + (ch ^ (row & 3)) * 8;
      __builtin_amdgcn_global_load_lds(
          (const __attribute__((address_space(1))) void*)ga,
          (__attribute__((address_space(3))) void*)(Ad + t * 16), 16, 0, 0);
    }
    char* Bd = Bs + buf * 32768;
    #pragma unroll
    for (int i = 0; i < 4; ++i) {
      const int c = t + i * 512;
      const int fr = c >> 2, ch = c & 3;
      const __hip_bfloat16* gb =
          WT + (size_t)fr * KK_ + kt * 32 + (ch ^ (fr & 3)) * 8;
      __builtin_amdgcn_global_load_lds(
          (const __attribute__((address_space(1))) void*)gb,
          (__attribute__((address_space(3))) void*)(Bd + c * 16), 16, 0, 0);
    }
  };

  stage(0, 0);
  __syncthreads();
  const int rA = lane & 15;
  const int offx = ((lane >> 4) * 16) ^ ((rA & 3) << 4);  // T2 read swizzle

  for (int kt = 0; kt < NKT; ++kt) {
    const int cur = kt & 1;
    if (kt < NKT - 1) stage(kt + 1, cur ^ 1);   // prefetch overlaps MFMA below
    const char* Ab = As + cur * 4096;
    const char* Bb = Bs + cur * 32768;
    bf16x8 af[2], bf[4];
    #pragma unroll
    for (int m = 0; m < 2; ++m)
      af[m] = *(const bf16x8*)(Ab + (m * 16 + rA) * 64 + offx);
    #pragma unroll
    for (int n = 0; n < 4; ++n)
      bf[n] = *(const bf16x8*)(Bb + (wn + n * 16 + rA) * 64 + offx);
    __builtin_amdgcn_s_setprio(1);
    #pragma unroll
    for (int m = 0; m < 2; ++m)
      #pragma unroll
      for (int n = 0; n < 4; ++n)
        acc[m][n] = __builtin_amdgcn_mfma_f32_16x16x32_bf16(af[m], bf[n], acc[m][n], 0, 0, 0);
    __builtin_amdgcn_s_setprio(0);
    __syncthreads();                   // drains prefetch; guards buf reuse
  }

  // ---------------- fused epilogue: bias + relu + LN (+ linear) --------------
  float* rS = (float*)smem;            // [8][32] row partial sums
  float* rQ = rS + 256;                // [8][32] row partial sumsq
  float* rP = rQ + 256;                // [8][32] row partial sum(v*g*wl)
  float* tS = rP + 256;                // [32] totals
  float* tQ = tS + 32;
  float* tP = tQ + 32;
  float* wG = tP + 32;                 // [8] per-wave sum g*wl
  float* wB = wG + 8;                  // [8] per-wave sum be*wl

  float bia[4], gg[4], bb[4], ww[4];
  #pragma unroll
  for (int n = 0; n < 4; ++n) {
    const int f = wn + n * 16 + rA;
    bia[n] = bias[f]; gg[n] = g[f]; bb[n] = be[f];
    if (MODE == 1) ww[n] = wl[f];
  }
  if (MODE == 1) {
    float gwp = 0.f, bwp = 0.f;
    #pragma unroll
    for (int n = 0; n < 4; ++n) { gwp += gg[n] * ww[n]; bwp += bb[n] * ww[n]; }
    #pragma unroll
    for (int o = 1; o < 16; o <<= 1) {
      gwp += __shfl_xor(gwp, o); bwp += __shfl_xor(bwp, o);
    }
    if (lane == 0) { wG[wave] = gwp; wB[wave] = bwp; }
  }
  #pragma unroll
  for (int m = 0; m < 2; ++m) {
    #pragma unroll
    for (int r = 0; r < 4; ++r) {
      float sv = 0.f, sq = 0.f, sp = 0.f;
      #pragma unroll
      for (int n = 0; n < 4; ++n) {
        float v = fmaxf(acc[m][n][r] + bia[n], 0.f);
        acc[m][n][r] = v;
        sv += v; sq += v * v;
        if (MODE == 1) sp += v * gg[n] * ww[n];
      }
      #pragma unroll
      for (int o = 1; o < 16; o <<= 1) {
        sv += __shfl_xor(sv, o); sq += __shfl_xor(sq, o);
        if (MODE == 1) sp += __shfl_xor(sp, o);
      }
      if (rA == 0) {
        const int row = m * 16 + (lane >> 4) * 4 + r;
        rS[wave * 32 + row] = sv; rQ[wave * 32 + row] = sq;
        if (MODE == 1) rP[wave * 32 + row] = sp;
      }
    }
  }
  __syncthreads();
  if (t < 32) {
    float S = 0.f, Q = 0.f, Pp = 0.f;
    #pragma unroll
    for (int w = 0; w < 8; ++w) {
      S += rS[w * 32 + t]; Q += rQ[w * 32 + t];
      if (MODE == 1) Pp += rP[w * 32 + t];
    }
    tS[t] = S; tQ[t] = Q;
    if (MODE == 1) tP[t] = Pp;
  }
  __syncthreads();
  if (MODE == 0) {
    unsigned short* Pu = (unsigned short*)Pout;
    #pragma unroll
    for (int m = 0; m < 2; ++m) {
      #pragma unroll
      for (int r = 0; r < 4; ++r) {
        const int row = m * 16 + (lane >> 4) * 4 + r;
        const float mean = tS[row] * (1.f / F_);
        const float var = tQ[row] * (1.f / F_) - mean * mean;
        const float inv = rsqrtf(var + 1e-5f);
        unsigned short* pp =
            Pu + ((size_t)b * SP_ + st + row + 1) * D_ + wn + rA;
        #pragma unroll
        for (int n = 0; n < 4; ++n)
          pp[n * 16] = f2bf((acc[m][n][r] - mean) * inv * gg[n] + bb[n]);
      }
    }
  } else {
    if (t < 32) {
      float GW = 0.f, BW = 0.f;
      #pragma unroll
      for (int w = 0; w < 8; ++w) { GW += wG[w]; BW += wB[w]; }
      const float mean = tS[t] * (1.f / F_);
      const float var = tQ[t] * (1.f / F_) - mean * mean;
      const float inv = rsqrtf(var + 1e-5f);
      const int grow = b * S_ + st + t;
      pred[grow] = mask[grow] ? 0.f
                              : (inv * tP[t] - inv * mean * GW + BW + bl[0]);
    }
  }
}

// ----- out[padded row] = bf16( in[padded row] + emb[searchsorted(truth)] ) ---
__global__ __launch_bounds__(128) void addemb_k(const __hip_bfloat16* __restrict__ in,
                                                const float* __restrict__ truth,
                                                const float* __restrict__ bins,
                                                const float* __restrict__ emb,
                                                __hip_bfloat16* __restrict__ outX) {
  const int row = blockIdx.x;  // b*S + s
  __shared__ int sidx;
  if (threadIdx.x == 0) {
    const float v = truth[row];
    int lo = 0, hi = 255;      // NB-1 bins
    while (lo < hi) { const int mid = (lo + hi) >> 1; if (bins[mid] < v) lo = mid + 1; else hi = mid; }
    sidx = lo;                 // searchsorted side='left'
  }
  __syncthreads();
  const int b = row >> 9, s = row & 511;
  const size_t off = ((size_t)b * SP_ + s + 1) * D_ + threadIdx.x * 4;
  const ushort4 ui = *(const ushort4*)((const unsigned short*)in + off);
  const float4 e = *(const float4*)(emb + (size_t)sidx * D_ + threadIdx.x * 4);
  ushort4 u = make_ushort4(f2bf(bf2f(ui.x) + e.x), f2bf(bf2f(ui.y) + e.y),
                           f2bf(bf2f(ui.z) + e.z), f2bf(bf2f(ui.w) + e.w));
  *(ushort4*)((unsigned short*)outX + off) = u;
}

// ------------- inclusive cumsum of durations per batch; mel_len as float -----
__global__ __launch_bounds__(512) void scan_k(const int* __restrict__ dur,
                                              int* __restrict__ cum,
                                              float* __restrict__ mel_len) {
  __shared__ int sh[S_];
  const int b = blockIdx.x, t = threadIdx.x;
  sh[t] = dur[b * S_ + t];
  __syncthreads();
  for (int off = 1; off < S_; off <<= 1) {
    const int add = (t >= off) ? sh[t - off] : 0;
    __syncthreads();
    sh[t] += add;
    __syncthreads();
  }
  cum[b * S_ + t] = sh[t];
  if (t == S_ - 1) mel_len[b] = (float)sh[t];
}

// --- length regulate (2 positions/block) + mel_mask -> float folded in ------
__global__ __launch_bounds__(256) void gather_k(const __hip_bfloat16* __restrict__ X,
                                                const int* __restrict__ cum,
                                                const unsigned char* __restrict__ melm,
                                                float* __restrict__ out,
                                                float* __restrict__ maskf) {
  const int b    = blockIdx.x >> 11;   // 2048 pairs per batch
  const int pos0 = (blockIdx.x & 2047) * 2;
  const int half = threadIdx.x >> 7;   // 0 or 1
  const int tl   = threadIdx.x & 127;
  const int pos  = pos0 + half;
  __shared__ int sidx[2], svalid[2];
  if (tl == 0) {
    const int* c = cum + b * S_;
    int lo = 0, hi = S_;
    while (lo < hi) {                  // upper_bound: first c[i] > pos
      const int mid = (lo + hi) >> 1;
      if (c[mid] <= pos) lo = mid + 1; else hi = mid;
    }
    sidx[half] = (lo < S_ - 1) ? lo : (S_ - 1);
    svalid[half] = (pos < c[S_ - 1]) ? 1 : 0;
    maskf[(size_t)b * T_ + pos] = melm[(size_t)b * T_ + pos] ? 1.f : 0.f;
  }
  __syncthreads();
  float4 v = make_float4(0.f, 0.f, 0.f, 0.f);
  if (svalid[half]) {
    const ushort4 u = *(const ushort4*)((const unsigned short*)X +
                        ((size_t)b * SP_ + sidx[half] + 1) * D_ + tl * 4);
    v = make_float4(bf2f(u.x), bf2f(u.y), bf2f(u.z), bf2f(u.w));
  }
  *(float4*)(out + ((size_t)b * T_ + pos) * D_ + tl * 4) = v;
}

extern "C" void kernel_launch(void* const* d_in, const int* in_sizes, int n_in,
                              void* d_out, int out_size, void* d_ws, size_t ws_size,
                              hipStream_t stream) {
  const float* x            = (const float*)d_in[0];
  const unsigned char* srcm = (const unsigned char*)d_in[1];
  const unsigned char* melm = (const unsigned char*)d_in[2];
  const float* pitch_truth  = (const float*)d_in[3];
  const float* energy_truth = (const float*)d_in[4];
  const int*   dur          = (const int*)d_in[5];
  const float* conv1_w = (const float*)d_in[6];
  const float* conv1_b = (const float*)d_in[7];
  const float* ln1_g   = (const float*)d_in[8];
  const float* ln1_b   = (const float*)d_in[9];
  const float* conv2_w = (const float*)d_in[10];
  const float* conv2_b = (const float*)d_in[11];
  const float* ln2_g   = (const float*)d_in[12];
  const float* ln2_b   = (const float*)d_in[13];
  const float* lin_w   = (const float*)d_in[14];
  const float* lin_b   = (const float*)d_in[15];
  const float* pitch_emb   = (const float*)d_in[16];
  const float* energy_emb  = (const float*)d_in[17];
  const float* pitch_bins  = (const float*)d_in[18];
  const float* energy_bins = (const float*)d_in[19];

  float* out      = (float*)d_out;
  float* x_out    = out;                               // 32*4096*512
  float* p_pitch  = out + (size_t)B_ * T_ * D_;
  float* p_energy = p_pitch + B_ * S_;
  float* p_dur    = p_energy + B_ * S_;
  float* p_mellen = p_dur + B_ * S_;
  float* p_mask   = p_mellen + B_;

  // ws: X0 | X | P (16.9MB bf16 padded each) | WT1 | WT2 (4.7MB) | cum (64KB)
  __hip_bfloat16* X0  = (__hip_bfloat16*)d_ws;
  __hip_bfloat16* X   = X0 + (size_t)B_ * SP_ * D_;
  __hip_bfloat16* P   = X + (size_t)B_ * SP_ * D_;
  __hip_bfloat16* WT1 = P + (size_t)B_ * SP_ * D_;
  __hip_bfloat16* WT2 = WT1 + (size_t)3 * F_ * KK_;
  int*  cum = (int*)(WT2 + (size_t)3 * F_ * KK_);

  const dim3 blk512t(512), blk256(256), blk128(128);
  const dim3 rowGrid(B_ * S_);               // 16384
  const dim3 convGrid(512);                  // 512 M-tiles of 32 rows

  const int convLds = 2 * (4096 + 32768);    // 72 KB -> 2 blocks/CU
  hipFuncSetAttribute((const void*)convfuse_k<0>,
                      hipFuncAttributeMaxDynamicSharedMemorySize, convLds);
  hipFuncSetAttribute((const void*)convfuse_k<1>,
                      hipFuncAttributeMaxDynamicSharedMemorySize, convLds);

  topad_k<<<dim3(B_ * S_ + 2 * B_), blk128, 0, stream>>>(x, X0, X, P);
  wtrans_k<<<dim3(6 * 24 * 8), blk256, 0, stream>>>(conv1_w, conv2_w, WT1, WT2);

  auto predictor = [&](const __hip_bfloat16* in, int i, float* pred) {
    convfuse_k<0><<<convGrid, blk512t, convLds, stream>>>(
        in, WT1 + (size_t)i * F_ * KK_, conv1_b + (size_t)i * F_,
        ln1_g + (size_t)i * F_, ln1_b + (size_t)i * F_,
        nullptr, nullptr, nullptr, P, nullptr);
    convfuse_k<1><<<convGrid, blk512t, convLds, stream>>>(
        P, WT2 + (size_t)i * F_ * KK_, conv2_b + (size_t)i * F_,
        ln2_g + (size_t)i * F_, ln2_b + (size_t)i * F_,
        lin_w + (size_t)i * F_, lin_b + i, srcm, nullptr, pred);
  };

  predictor(X0, 0, p_pitch);
  addemb_k<<<rowGrid, blk128, 0, stream>>>(X0, pitch_truth, pitch_bins, pitch_emb, X);
  predictor(X, 1, p_energy);
  addemb_k<<<rowGrid, blk128, 0, stream>>>(X, energy_truth, energy_bins, energy_emb, X);
  predictor(X, 2, p_dur);

  scan_k<<<dim3(B_), blk512t, 0, stream>>>(dur, cum, p_mellen);
  gather_k<<<dim3(B_ * T_ / 2), blk256, 0, stream>>>(X, cum, melm, x_out, p_mask);
}

// Round 11
// 369.711 us; speedup vs baseline: 1.3975x; 1.3975x over previous
//
#include <hip/hip_runtime.h>
#include <hip/hip_bf16.h>

// VarianceAdaptor: 3x (conv1d->relu->LN->conv1d->relu->LN->linear) predictors,
// embedding adds between them, then length-regulate.
// Shapes fixed: B=32, S=512, D=F=512, K=3, T=4096, NB=256.
// Round 11: conv reverted to R9 (BM=64xBN=512 fused LN/linear, ~46us/conv —
// R10's BM=32 occupancy experiment regressed). Timeline compaction:
// prep_k = topad+wtrans+scan in one dispatch; addemb folded into conv2's
// epilogue (same rows, disjoint buffers). 12 -> 8 dispatches.

#define B_ 32
#define S_ 512
#define D_ 512
#define F_ 512
#define T_ 4096
#define SP_ 514           // padded rows per batch (row0 and row513 are zeros)
#define KK_ 1536          // 3*512 contraction length
#define NKT 24            // 1536/64 K-tiles

typedef __attribute__((ext_vector_type(8))) short bf16x8;
typedef __attribute__((ext_vector_type(4))) float f32x4;

__device__ __forceinline__ float bf2f(unsigned short u) {
  union { unsigned int i; float f; } c; c.i = (unsigned int)u << 16; return c.f;
}
__device__ __forceinline__ unsigned short f2bf(float f) {
  __hip_bfloat16 h = __float2bfloat16(f);
  return *(unsigned short*)&h;
}

// ---- prep: wtrans (blocks 0..1151) | topad (next 8224) | scan (last 32) ----
#define WT_BLKS 1152
#define TP_BLKS 8224      // (16384 rows + 64 pad tasks) / 2
__global__ __launch_bounds__(256) void prep_k(const float* __restrict__ x,
                                              const float* __restrict__ W1,
                                              const float* __restrict__ W2,
                                              const int* __restrict__ dur,
                                              __hip_bfloat16* __restrict__ X0,
                                              __hip_bfloat16* __restrict__ X,
                                              __hip_bfloat16* __restrict__ P,
                                              __hip_bfloat16* __restrict__ WT1,
                                              __hip_bfloat16* __restrict__ WT2,
                                              int* __restrict__ cum,
                                              float* __restrict__ mel_len) {
  const int blk = blockIdx.x;
  const int t = threadIdx.x;
  if (blk < WT_BLKS) {
    // ---- W [1536][512] fp32 -> WT [512][1536] bf16 (6 matrices) ----
    __shared__ float tb[64][65];
    const int w = blk / 192;
    const int kt = (blk % 192) >> 3;   // 24 kk-tiles of 64
    const int ft = blk & 7;            // 8 f-tiles of 64
    const float* src = (w < 3) ? (W1 + (size_t)w * KK_ * F_)
                               : (W2 + (size_t)(w - 3) * KK_ * F_);
    __hip_bfloat16* dst = (w < 3) ? (WT1 + (size_t)w * KK_ * F_)
                                  : (WT2 + (size_t)(w - 3) * KK_ * F_);
    const int ty = t >> 4, tx = t & 15;
    #pragma unroll
    for (int j = 0; j < 4; ++j) {
      const int r = ty + j * 16;       // kk within tile
      const float4 v = *(const float4*)(src + (size_t)(kt * 64 + r) * F_ + ft * 64 + tx * 4);
      tb[r][tx * 4 + 0] = v.x; tb[r][tx * 4 + 1] = v.y;
      tb[r][tx * 4 + 2] = v.z; tb[r][tx * 4 + 3] = v.w;
    }
    __syncthreads();
    #pragma unroll
    for (int j = 0; j < 4; ++j) {
      const int r = ty + j * 16;       // f within tile
      ushort4 u = make_ushort4(f2bf(tb[tx * 4 + 0][r]), f2bf(tb[tx * 4 + 1][r]),
                               f2bf(tb[tx * 4 + 2][r]), f2bf(tb[tx * 4 + 3][r]));
      *(ushort4*)((unsigned short*)dst + (size_t)(ft * 64 + r) * KK_ + kt * 64 + tx * 4) = u;
    }
  } else if (blk < WT_BLKS + TP_BLKS) {
    // ---- fp32 x -> bf16 padded X0 rows; pad-row zeroing of X0/X/P ----
    const int task = (blk - WT_BLKS) * 2 + (t >> 7);   // 2 tasks per block
    const int tl = t & 127;
    if (task < B_ * S_) {
      const int b = task >> 9, s = task & 511;
      const float4 v = *(const float4*)(x + (size_t)task * D_ + tl * 4);
      ushort4 u = make_ushort4(f2bf(v.x), f2bf(v.y), f2bf(v.z), f2bf(v.w));
      *(ushort4*)((unsigned short*)X0 + ((size_t)b * SP_ + s + 1) * D_ + tl * 4) = u;
    } else {
      const int idx = task - B_ * S_;  // 0..63 pad tasks
      const int b = idx >> 1;
      const int r = (idx & 1) ? (SP_ - 1) : 0;
      const size_t off = ((size_t)b * SP_ + r) * D_ + tl * 4;
      const ushort4 z = make_ushort4(0, 0, 0, 0);
      *(ushort4*)((unsigned short*)X0 + off) = z;
      *(ushort4*)((unsigned short*)X + off) = z;
      *(ushort4*)((unsigned short*)P + off) = z;
    }
  } else {
    // ---- inclusive cumsum of durations (256 threads, 512 elems) ----
    __shared__ int sh[S_];
    const int b = blk - (WT_BLKS + TP_BLKS);
    sh[t] = dur[b * S_ + t];
    sh[t + 256] = dur[b * S_ + t + 256];
    __syncthreads();
    for (int off = 1; off < S_; off <<= 1) {
      const int a1 = (t >= off) ? sh[t - off] : 0;
      const int j2 = t + 256;
      const int a2 = (j2 >= off) ? sh[j2 - off] : 0;
      __syncthreads();
      sh[t] += a1; sh[j2] += a2;
      __syncthreads();
    }
    cum[b * S_ + t] = sh[t];
    cum[b * S_ + t + 256] = sh[t + 256];
    if (t == 255) mel_len[b] = (float)sh[S_ - 1];
  }
}

// ----- conv + bias + relu + LayerNorm fused. MODE 0: -> bf16 padded Pout.
// ----- MODE 1: + linear head -> pred; optional fused addemb (rows st..st+63).
// Y[b*512+st+i][f] = sum_{tap,d} Pin[b][st+i+tap][d] * WT[f][tap*512+d]
template <int MODE>
__global__ __launch_bounds__(512, 1) void convfuse_k(
    const __hip_bfloat16* __restrict__ Pin,
    const __hip_bfloat16* __restrict__ WT,
    const float* __restrict__ bias,
    const float* __restrict__ g,
    const float* __restrict__ be,
    const float* __restrict__ wl,
    const float* __restrict__ bl,
    const unsigned char* __restrict__ mask,
    __hip_bfloat16* __restrict__ Pout,
    float* __restrict__ pred,
    const float* __restrict__ truth,       // addemb (MODE 1, may be null)
    const float* __restrict__ bins,
    const float* __restrict__ embp,
    const __hip_bfloat16* __restrict__ Xsrc,
    __hip_bfloat16* __restrict__ Xdst) {
  extern __shared__ char smem[];
  char* As = smem;                     // 2 x 8192  [64 rows][128 B]
  char* Bs = smem + 2 * 8192;          // 2 x 65536 [512 f][128 B]
  // T1: XCD swizzle (256 blocks, 8 XCDs -> 32 contiguous M-tiles per XCD).
  const int swz = (blockIdx.x & 7) * 32 + (blockIdx.x >> 3);
  const int b  = swz >> 3;             // 8 M-tiles per batch
  const int st = (swz & 7) * 64;
  const int t = threadIdx.x;
  const int lane = t & 63;
  const int wave = t >> 6;
  const int wn = wave * 64;            // wave's 64-col slice; all waves same rows

  f32x4 acc[4][4];
  #pragma unroll
  for (int m = 0; m < 4; ++m)
    #pragma unroll
    for (int n = 0; n < 4; ++n) acc[m][n] = (f32x4){0.f, 0.f, 0.f, 0.f};

  const __hip_bfloat16* Xb = Pin + (size_t)b * SP_ * D_;

  // Stage: A 512 chunks (1/thread), B 4096 chunks (8/thread); all wave-uniform
  // => exact vmcnt counting. T2: pre-swizzled global source ch^(row&7),
  // lane-linear LDS dest (global_load_lds contract).
  auto stage = [&](int kt, int buf) {
    const int tap = kt >> 3, d0 = (kt & 7) * 64;
    const __hip_bfloat16* Arow = Xb + (size_t)(st + tap) * D_ + d0;
    char* Ad = As + buf * 8192;
    {
      const int row = t >> 3, ch = t & 7;
      const __hip_bfloat16* ga = Arow + (size_t)row * D_ + (ch ^ (row & 7)) * 8;
      __builtin_amdgcn_global_load_lds(
          (const __attribute__((address_space(1))) void*)ga,
          (__attribute__((address_space(3))) void*)(Ad + t * 16), 16, 0, 0);
    }
    char* Bd = Bs + buf * 65536;
    #pragma unroll
    for (int i = 0; i < 8; ++i) {
      const int c = t + i * 512;
      const int fr = c >> 3, ch = c & 7;
      const __hip_bfloat16* gb = WT + (size_t)fr * KK_ + kt * 64 + (ch ^ (fr & 7)) * 8;
      __builtin_amdgcn_global_load_lds(
          (const __attribute__((address_space(1))) void*)gb,
          (__attribute__((address_space(3))) void*)(Bd + c * 16), 16, 0, 0);
    }
  };

  stage(0, 0);
  const int rA = lane & 15;
  const int kc16 = (lane >> 4) * 16;
  const int sw = (rA & 7) << 4;        // T2 read swizzle

  for (int kt = 0; kt < NKT; ++kt) {
    const int cur = kt & 1;
    if (kt < NKT - 1) {
      stage(kt + 1, cur ^ 1);          // 9 loads stay in flight across barrier
      asm volatile("s_waitcnt vmcnt(9)" ::: "memory");  // stage(kt) retired
    } else {
      asm volatile("s_waitcnt vmcnt(0)" ::: "memory");
    }
    __builtin_amdgcn_s_barrier();
    __builtin_amdgcn_sched_barrier(0);
    const char* Ab = As + cur * 8192;
    const char* Bb = Bs + cur * 65536;
    #pragma unroll
    for (int kh = 0; kh < 2; ++kh) {
      const int offx = (kh * 64 + kc16) ^ sw;
      bf16x8 af[4], bf[4];
      #pragma unroll
      for (int m = 0; m < 4; ++m)
        af[m] = *(const bf16x8*)(Ab + (m * 16 + rA) * 128 + offx);
      #pragma unroll
      for (int n = 0; n < 4; ++n)
        bf[n] = *(const bf16x8*)(Bb + (wn + n * 16 + rA) * 128 + offx);
      __builtin_amdgcn_s_setprio(1);
      #pragma unroll
      for (int m = 0; m < 4; ++m)
        #pragma unroll
        for (int n = 0; n < 4; ++n)
          acc[m][n] = __builtin_amdgcn_mfma_f32_16x16x32_bf16(af[m], bf[n], acc[m][n], 0, 0, 0);
      __builtin_amdgcn_s_setprio(0);
    }
    __builtin_amdgcn_sched_barrier(0);
    __builtin_amdgcn_s_barrier();      // all reads of buf cur done before restage
  }

  // ---------------- fused epilogue: bias + relu + LN (+ linear) --------------
  float* rS = (float*)smem;            // [8][64] row partial sums
  float* rQ = rS + 512;                // [8][64] row partial sumsq
  float* rP = rQ + 512;                // [8][64] row partial sum(v*g*wl)
  float* tS = rP + 512;                // [64] totals
  float* tQ = tS + 64;
  float* tP = tQ + 64;
  float* wG = tP + 64;                 // [8] per-wave sum g*wl
  float* wB = wG + 8;                  // [8] per-wave sum be*wl

  float bia[4], gg[4], bb[4], ww[4];
  #pragma unroll
  for (int n = 0; n < 4; ++n) {
    const int f = wn + n * 16 + rA;
    bia[n] = bias[f]; gg[n] = g[f]; bb[n] = be[f];
    if (MODE == 1) ww[n] = wl[f];
  }
  if (MODE == 1) {
    float gwp = 0.f, bwp = 0.f;
    #pragma unroll
    for (int n = 0; n < 4; ++n) { gwp += gg[n] * ww[n]; bwp += bb[n] * ww[n]; }
    #pragma unroll
    for (int o = 1; o < 16; o <<= 1) {
      gwp += __shfl_xor(gwp, o); bwp += __shfl_xor(bwp, o);
    }
    if (lane == 0) { wG[wave] = gwp; wB[wave] = bwp; }
  }
  // relu + per-(m,r) row partials over this wave's 64 cols
  #pragma unroll
  for (int m = 0; m < 4; ++m) {
    #pragma unroll
    for (int r = 0; r < 4; ++r) {
      float sv = 0.f, sq = 0.f, sp = 0.f;
      #pragma unroll
      for (int n = 0; n < 4; ++n) {
        float v = fmaxf(acc[m][n][r] + bia[n], 0.f);
        acc[m][n][r] = v;
        sv += v; sq += v * v;
        if (MODE == 1) sp += v * gg[n] * ww[n];
      }
      #pragma unroll
      for (int o = 1; o < 16; o <<= 1) {
        sv += __shfl_xor(sv, o); sq += __shfl_xor(sq, o);
        if (MODE == 1) sp += __shfl_xor(sp, o);
      }
      if (rA == 0) {
        const int row = m * 16 + (lane >> 4) * 4 + r;
        rS[wave * 64 + row] = sv; rQ[wave * 64 + row] = sq;
        if (MODE == 1) rP[wave * 64 + row] = sp;
      }
    }
  }
  __syncthreads();
  if (t < 64) {
    float S = 0.f, Q = 0.f, Pp = 0.f;
    #pragma unroll
    for (int w = 0; w < 8; ++w) {
      S += rS[w * 64 + t]; Q += rQ[w * 64 + t];
      if (MODE == 1) Pp += rP[w * 64 + t];
    }
    tS[t] = S; tQ[t] = Q;
    if (MODE == 1) tP[t] = Pp;
  }
  __syncthreads();
  if (MODE == 0) {
    unsigned short* Pu = (unsigned short*)Pout;
    #pragma unroll
    for (int m = 0; m < 4; ++m) {
      #pragma unroll
      for (int r = 0; r < 4; ++r) {
        const int row = m * 16 + (lane >> 4) * 4 + r;
        const float mean = tS[row] * (1.f / F_);
        const float var = tQ[row] * (1.f / F_) - mean * mean;
        const float inv = rsqrtf(var + 1e-5f);
        unsigned short* pp =
            Pu + ((size_t)b * SP_ + st + row + 1) * D_ + wn + rA;
        #pragma unroll
        for (int n = 0; n < 4; ++n)
          pp[n * 16] = f2bf((acc[m][n][r] - mean) * inv * gg[n] + bb[n]);
      }
    }
  } else {
    if (t < 64) {
      float GW = 0.f, BW = 0.f;
      #pragma unroll
      for (int w = 0; w < 8; ++w) { GW += wG[w]; BW += wB[w]; }
      const float mean = tS[t] * (1.f / F_);
      const float var = tQ[t] * (1.f / F_) - mean * mean;
      const float inv = rsqrtf(var + 1e-5f);
      const int grow = b * S_ + st + t;
      pred[grow] = mask[grow] ? 0.f
                              : (inv * tP[t] - inv * mean * GW + BW + bl[0]);
    }
    // ------- fused addemb for this block's rows (disjoint buffers) ----------
    if (truth != nullptr) {
      __syncthreads();
      int* aidx = (int*)(smem + 8192);
      if (t < 64) {
        const float v = truth[b * S_ + st + t];
        int lo = 0, hi = 255;          // NB-1 bins
        while (lo < hi) { const int mid = (lo + hi) >> 1; if (bins[mid] < v) lo = mid + 1; else hi = mid; }
        aidx[t] = lo;                  // searchsorted side='left'
      }
      __syncthreads();
      const int sub = t >> 7;          // 4 rows per pass
      const int tl = t & 127;
      #pragma unroll
      for (int it = 0; it < 16; ++it) {
        const int r = it * 4 + sub;
        const int e = aidx[r];
        const size_t off = ((size_t)b * SP_ + st + r + 1) * D_ + tl * 4;
        const ushort4 ui = *(const ushort4*)((const unsigned short*)Xsrc + off);
        const float4 ev = *(const float4*)(embp + (size_t)e * D_ + tl * 4);
        ushort4 u = make_ushort4(f2bf(bf2f(ui.x) + ev.x), f2bf(bf2f(ui.y) + ev.y),
                                 f2bf(bf2f(ui.z) + ev.z), f2bf(bf2f(ui.w) + ev.w));
        *(ushort4*)((unsigned short*)Xdst + off) = u;
      }
    }
  }
}

// --- length regulate (2 positions/block) + mel_mask -> float folded in ------
__global__ __launch_bounds__(256) void gather_k(const __hip_bfloat16* __restrict__ X,
                                                const int* __restrict__ cum,
                                                const unsigned char* __restrict__ melm,
                                                float* __restrict__ out,
                                                float* __restrict__ maskf) {
  const int b    = blockIdx.x >> 11;   // 2048 pairs per batch
  const int pos0 = (blockIdx.x & 2047) * 2;
  const int half = threadIdx.x >> 7;   // 0 or 1
  const int tl   = threadIdx.x & 127;
  const int pos  = pos0 + half;
  __shared__ int sidx[2], svalid[2];
  if (tl == 0) {
    const int* c = cum + b * S_;
    int lo = 0, hi = S_;
    while (lo < hi) {                  // upper_bound: first c[i] > pos
      const int mid = (lo + hi) >> 1;
      if (c[mid] <= pos) lo = mid + 1; else hi = mid;
    }
    sidx[half] = (lo < S_ - 1) ? lo : (S_ - 1);
    svalid[half] = (pos < c[S_ - 1]) ? 1 : 0;
    maskf[(size_t)b * T_ + pos] = melm[(size_t)b * T_ + pos] ? 1.f : 0.f;
  }
  __syncthreads();
  float4 v = make_float4(0.f, 0.f, 0.f, 0.f);
  if (svalid[half]) {
    const ushort4 u = *(const ushort4*)((const unsigned short*)X +
                        ((size_t)b * SP_ + sidx[half] + 1) * D_ + tl * 4);
    v = make_float4(bf2f(u.x), bf2f(u.y), bf2f(u.z), bf2f(u.w));
  }
  *(float4*)(out + ((size_t)b * T_ + pos) * D_ + tl * 4) = v;
}

extern "C" void kernel_launch(void* const* d_in, const int* in_sizes, int n_in,
                              void* d_out, int out_size, void* d_ws, size_t ws_size,
                              hipStream_t stream) {
  const float* x            = (const float*)d_in[0];
  const unsigned char* srcm = (const unsigned char*)d_in[1];
  const unsigned char* melm = (const unsigned char*)d_in[2];
  const float* pitch_truth  = (const float*)d_in[3];
  const float* energy_truth = (const float*)d_in[4];
  const int*   dur          = (const int*)d_in[5];
  const float* conv1_w = (const float*)d_in[6];
  const float* conv1_b = (const float*)d_in[7];
  const float* ln1_g   = (const float*)d_in[8];
  const float* ln1_b   = (const float*)d_in[9];
  const float* conv2_w = (const float*)d_in[10];
  const float* conv2_b = (const float*)d_in[11];
  const float* ln2_g   = (const float*)d_in[12];
  const float* ln2_b   = (const float*)d_in[13];
  const float* lin_w   = (const float*)d_in[14];
  const float* lin_b   = (const float*)d_in[15];
  const float* pitch_emb   = (const float*)d_in[16];
  const float* energy_emb  = (const float*)d_in[17];
  const float* pitch_bins  = (const float*)d_in[18];
  const float* energy_bins = (const float*)d_in[19];

  float* out      = (float*)d_out;
  float* x_out    = out;                               // 32*4096*512
  float* p_pitch  = out + (size_t)B_ * T_ * D_;
  float* p_energy = p_pitch + B_ * S_;
  float* p_dur    = p_energy + B_ * S_;
  float* p_mellen = p_dur + B_ * S_;
  float* p_mask   = p_mellen + B_;

  // ws: X0 | X | P (16.9MB bf16 padded each) | WT1 | WT2 (4.7MB) | cum (64KB)
  __hip_bfloat16* X0  = (__hip_bfloat16*)d_ws;
  __hip_bfloat16* X   = X0 + (size_t)B_ * SP_ * D_;
  __hip_bfloat16* P   = X + (size_t)B_ * SP_ * D_;
  __hip_bfloat16* WT1 = P + (size_t)B_ * SP_ * D_;
  __hip_bfloat16* WT2 = WT1 + (size_t)3 * F_ * KK_;
  int*  cum = (int*)(WT2 + (size_t)3 * F_ * KK_);

  const dim3 blk512t(512), blk256(256);
  const dim3 convGrid(256);                  // 256 M-tiles of 64 rows

  const int convLds = 2 * (8192 + 65536);    // 144 KB
  hipFuncSetAttribute((const void*)convfuse_k<0>,
                      hipFuncAttributeMaxDynamicSharedMemorySize, convLds);
  hipFuncSetAttribute((const void*)convfuse_k<1>,
                      hipFuncAttributeMaxDynamicSharedMemorySize, convLds);

  prep_k<<<dim3(WT_BLKS + TP_BLKS + B_), blk256, 0, stream>>>(
      x, conv1_w, conv2_w, dur, X0, X, P, WT1, WT2, cum, p_mellen);

  auto predictor = [&](const __hip_bfloat16* in, int i, float* pred,
                       const float* truth, const float* bins, const float* emb,
                       const __hip_bfloat16* Xsrc, __hip_bfloat16* Xdst) {
    convfuse_k<0><<<convGrid, blk512t, convLds, stream>>>(
        in, WT1 + (size_t)i * F_ * KK_, conv1_b + (size_t)i * F_,
        ln1_g + (size_t)i * F_, ln1_b + (size_t)i * F_,
        nullptr, nullptr, nullptr, P, nullptr,
        nullptr, nullptr, nullptr, nullptr, nullptr);
    convfuse_k<1><<<convGrid, blk512t, convLds, stream>>>(
        P, WT2 + (size_t)i * F_ * KK_, conv2_b + (size_t)i * F_,
        ln2_g + (size_t)i * F_, ln2_b + (size_t)i * F_,
        lin_w + (size_t)i * F_, lin_b + i, srcm, nullptr, pred,
        truth, bins, emb, Xsrc, Xdst);
  };

  predictor(X0, 0, p_pitch, pitch_truth, pitch_bins, pitch_emb, X0, X);
  predictor(X, 1, p_energy, energy_truth, energy_bins, energy_emb, X, X);
  predictor(X, 2, p_dur, nullptr, nullptr, nullptr, nullptr, nullptr);

  gather_k<<<dim3(B_ * T_ / 2), blk256, 0, stream>>>(X, cum, melm, x_out, p_mask);
}